// Round 15
// baseline (484.802 us; speedup 1.0000x reference)
//
#include <hip/hip_runtime.h>
#include <math.h>

// Problem constants
#define BB 16
#define NN 1024
#define DD 256
#define HH 8
#define DHH 32
#define KNBR 16
#define MM (BB*NN)   // 16384 tokens

typedef __attribute__((ext_vector_type(8))) short  bf16x8;
typedef __attribute__((ext_vector_type(4))) float  f32x4;
typedef __attribute__((ext_vector_type(2))) unsigned short u16x2;
typedef __attribute__((ext_vector_type(4))) unsigned short u16x4;

// ---------------- workspace layout (bytes) ----------------
#define OFF_FLAG 0
#define OFF_CNT  ((size_t)256)                          // cnt_qkv[16] + cnt_attn[128]
#define OFF_XPE  ((size_t)1280)                         // bf16 x+pe (8 MB)
#define OFF_XBF  (OFF_XPE + (size_t)MM*DD*2)            // bf16 x    (8 MB)
#define OFF_WT   (OFF_XBF + (size_t)MM*DD*2)            // bf16 WT[4][256][256]
#define OFF_Q    (OFF_WT  + (size_t)4*DD*DD*2)
#define OFF_K    (OFF_Q   + (size_t)MM*DD*2)
#define OFF_V    (OFF_K   + (size_t)MM*DD*2)
#define OFF_IDX  (OFF_V   + (size_t)MM*DD*2)
#define OFF_AO   (OFF_IDX + (size_t)MM*KNBR*4)          // aobf: own region
#define WS_NEED  (OFF_AO  + (size_t)MM*DD*2)

// ---------------- helpers ----------------
__device__ __forceinline__ float bf2f(unsigned short u) {
    unsigned x = ((unsigned)u) << 16;
    return __builtin_bit_cast(float, x);
}
__device__ __forceinline__ unsigned short f2bf(float f) {
    unsigned x = __builtin_bit_cast(unsigned, f);
    unsigned r = (x + 0x7fffu + ((x >> 16) & 1u)) >> 16;   // RNE
    return (unsigned short)r;
}
__device__ __forceinline__ int mbcnt64(unsigned long long b) {
    return __builtin_amdgcn_mbcnt_hi((unsigned)(b >> 32),
           __builtin_amdgcn_mbcnt_lo((unsigned)b, 0));
}
__device__ __forceinline__ int get_valid(const void* m, int i, int u8) {
    if (u8) return ((const unsigned char*)m)[i] != 0;
    return ((const unsigned*)m)[i] != 0u;
}

// ---------------- fused prep (R13-proven) + counter zeroing ----------------
// block 0: mask detect + zero gate counters | [1,4097): KNN | [4097,5121): cvtW
// [5121,13313): PE+cvt (unmasked pe is output-invariant — proven R9/R10)
__global__ __launch_bounds__(256, 8) void prep_fused(
    const float* __restrict__ xpos, int* __restrict__ idxout,
    const float* __restrict__ x, const void* __restrict__ mask,
    int* __restrict__ flag, int* __restrict__ cnt,
    const float* __restrict__ Wq, const float* __restrict__ Wk,
    const float* __restrict__ Wv, const float* __restrict__ Wo,
    unsigned short* __restrict__ WT,
    unsigned short* __restrict__ xpebf, unsigned short* __restrict__ xbf) {
    __shared__ float4   sp[NN];          // 16 KB (knn)
    __shared__ unsigned scand[4][64];    // 1 KB  (knn)
    int bid = blockIdx.x;
    int tid = threadIdx.x;

    if (bid == 0) {
        if (tid < 144) cnt[tid] = 0;     // gate counters (visible at kernel boundary)
        __shared__ int s_u8, s_f32;
        if (tid == 0) { s_u8 = 0; s_f32 = 0; }
        __syncthreads();
        int u8 = 0, f32 = 0;
        const unsigned* mraw = (const unsigned*)mask;
        for (int i = tid; i < 4096; i += 256) {
            unsigned w = mraw[i];
            if (w == 0x3f800000u) f32 = 1;
            else if (w > 1u) u8 = 1;
        }
        if (u8)  atomicOr(&s_u8, 1);
        if (f32) atomicOr(&s_f32, 1);
        __syncthreads();
        if (tid == 0) *flag = (s_f32 ? 0 : (s_u8 ? 1 : 0));
        return;
    }
    if (bid >= 5121) {
        int pb = bid - 5121;
        int t = pb * 2 + (tid >> 7);
        int p = tid & 127;
        int half = p >> 6;
        int j = p & 63;
        float pos = xpos[(size_t)t*3 + (half ? 0 : 1)];
        float recip = 6.2831853071795864f * exp2f(-(float)j * 0.20762050593045952f);
        float th = pos * recip;
        float s, c;
        __sincosf(th, &s, &c);
        size_t o = (size_t)t*DD + half*128 + 2*j;
        float2 xv = *(const float2*)(x + o);
        u16x2 xb; xb[0] = f2bf(xv.x);     xb[1] = f2bf(xv.y);
        u16x2 xp; xp[0] = f2bf(xv.x + s); xp[1] = f2bf(xv.y + c);
        *(u16x2*)(xbf + o)   = xb;
        *(u16x2*)(xpebf + o) = xp;
        return;
    }
    if (bid >= 4097) {
        int g = bid - 4097;
        int wsel = g >> 8;
        int kk = g & 255;
        const float* W = (wsel == 0) ? Wq : (wsel == 1) ? Wk : (wsel == 2) ? Wv : Wo;
        WT[(size_t)wsel*65536 + (size_t)tid*256 + kk] = f2bf(W[(size_t)kk*256 + tid]);
        return;
    }

    // ---- KNN (proven R7 algorithm) ----
    int kb = bid - 1;
    int nblk = kb & 255;
    int b    = kb >> 8;
    for (int i = tid; i < NN; i += 256) {
        const float* p = xpos + ((size_t)b*NN + i)*3;
        float px = p[0], py = p[1], pz = p[2];
        sp[i] = make_float4(px, py, pz, px*px + py*py + pz*pz);
    }
    __syncthreads();
    int wave = tid >> 6, lane = tid & 63;
    int n = nblk * 4 + wave;
    float4 qp = sp[n];
    float d[16];
    #pragma unroll
    for (int t = 0; t < 16; ++t) {
        float4 pm = sp[lane + 64*t];
        float dot = qp.x*pm.x + qp.y*pm.y + qp.z*pm.z;
        float d2 = qp.w + pm.w - 2.f*dot;              // exact reference formula
        d[t] = fmaxf(d2, 0.f);
    }
    float lmin = d[0];
    #pragma unroll
    for (int t = 1; t < 16; ++t) lmin = fminf(lmin, d[t]);
    float xs = lmin;
    #pragma unroll
    for (int kk = 2; kk <= 64; kk <<= 1) {
        #pragma unroll
        for (int j = kk >> 1; j >= 1; j >>= 1) {
            float vv = __shfl_xor(xs, j);
            bool up = ((lane & kk) == 0);
            bool lower = ((lane & j) == 0);
            xs = (up == lower) ? fminf(xs, vv) : fmaxf(xs, vv);
        }
    }
    float tau = __shfl(xs, 15);
    int T = 0;
    #pragma unroll
    for (int t = 0; t < 16; ++t) T += (d[t] <= tau) ? 1 : 0;
    #pragma unroll
    for (int off = 1; off <= 32; off <<= 1) T += __shfl_xor(T, off);

    bool fast = (T <= 64);
    if (fast) {
        int base = 0;
        #pragma unroll
        for (int t = 0; t < 16; ++t) {
            bool c = (d[t] <= tau);
            unsigned long long bb = __ballot(c);
            if (c) scand[wave][base + mbcnt64(bb)] = __builtin_bit_cast(unsigned, d[t]);
            base += (int)__popcll(bb);
        }
    }
    __syncthreads();

    int out_base = (b*NN + n) * KNBR;
    if (fast) {
        unsigned key = (lane < T) ? scand[wave][lane] : 0xFFFFFFFFu;
        #pragma unroll
        for (int kk = 2; kk <= 64; kk <<= 1) {
            #pragma unroll
            for (int j = kk >> 1; j >= 1; j >>= 1) {
                unsigned vv = (unsigned)__shfl_xor((int)key, j);
                bool up = ((lane & kk) == 0);
                bool lower = ((lane & j) == 0);
                bool takemin = (up == lower);
                key = (takemin == (key < vv)) ? key : vv;
            }
        }
        unsigned tau2 = (unsigned)__shfl((int)key, 15);   // exact v16
        int c1 = (int)__popcll(__ballot(key < tau2));
        int lt_base = 0, eq_seen = 0;
        #pragma unroll
        for (int t = 0; t < 16; ++t) {
            unsigned du = __builtin_bit_cast(unsigned, d[t]);
            bool lt = du < tau2;
            bool eq = du == tau2;
            unsigned long long blt = __ballot(lt);
            unsigned long long beq = __ballot(eq);
            if (lt) idxout[out_base + lt_base + mbcnt64(blt)] = lane + 64*t;
            int er = eq_seen + mbcnt64(beq);
            if (eq && (c1 + er) < KNBR) idxout[out_base + c1 + er] = lane + 64*t;
            lt_base += (int)__popcll(blt);
            eq_seen += (int)__popcll(beq);
        }
    } else {
        #pragma unroll 1
        for (int it = 0; it < KNBR; ++it) {
            float bd = 3.4e38f; int bm = 1 << 30;
            #pragma unroll
            for (int t = 0; t < 16; ++t)
                if (d[t] < bd) { bd = d[t]; bm = lane + 64*t; }
            #pragma unroll
            for (int off = 32; off >= 1; off >>= 1) {
                float od = __shfl_xor(bd, off);
                int   om = __shfl_xor(bm, off);
                if (od < bd || (od == bd && om < bm)) { bd = od; bm = om; }
            }
            if (lane == 0) idxout[out_base + it] = bm;
            int sel = bm >> 6;
            int mine = ((bm & 63) == lane);
            #pragma unroll
            for (int t = 0; t < 16; ++t)
                if (mine && t == sel) d[t] = 3.4e38f;
        }
    }
}

// ---------------- bf16 MFMA GEMM core (R8/R10-proven) ----------------
template<int EPI>
__device__ __forceinline__ void gemm_mfma_core(
    const unsigned short* __restrict__ A, const unsigned short* __restrict__ BT,
    void* __restrict__ C, const unsigned short* __restrict__ residbf,
    const void* __restrict__ mask, int u8, int bm, int bn, char* smem) {
    unsigned short (*As)[32] = (unsigned short (*)[32])smem;
    unsigned short (*Bs)[32] = (unsigned short (*)[32])(smem + 8192);
    int tid = threadIdx.x;
    int w = tid >> 6, l = tid & 63;
    int wr = w >> 1, wc = w & 1;

    f32x4 acc[4][4] = {};

    for (int kt = 0; kt < 8; ++kt) {
        #pragma unroll
        for (int j = 0; j < 2; ++j) {
            int c  = (w + j*4)*64 + l;
            int row = c >> 2;
            int cb  = (c & 3) * 16;
            const char* ga = (const char*)A + ((size_t)(bm + row)*256 + kt*32)*2 + cb;
            char* la = (char*)As + (size_t)(w + j*4)*1024;
            __builtin_amdgcn_global_load_lds(
                (const __attribute__((address_space(1))) unsigned*)ga,
                (__attribute__((address_space(3))) unsigned*)la, 16, 0, 0);
            const char* gb = (const char*)BT + ((size_t)(bn + row)*256 + kt*32)*2 + cb;
            char* lb = (char*)Bs + (size_t)(w + j*4)*1024;
            __builtin_amdgcn_global_load_lds(
                (const __attribute__((address_space(1))) unsigned*)gb,
                (__attribute__((address_space(3))) unsigned*)lb, 16, 0, 0);
        }
        __syncthreads();

        bf16x8 af[4], bfr[4];
        #pragma unroll
        for (int m = 0; m < 4; ++m)
            af[m] = *(const bf16x8*)&As[wr*64 + m*16 + (l & 15)][(l >> 4) * 8];
        #pragma unroll
        for (int n = 0; n < 4; ++n)
            bfr[n] = *(const bf16x8*)&Bs[wc*64 + n*16 + (l & 15)][(l >> 4) * 8];
        #pragma unroll
        for (int m = 0; m < 4; ++m)
            #pragma unroll
            for (int n = 0; n < 4; ++n)
                acc[m][n] = __builtin_amdgcn_mfma_f32_16x16x32_bf16(af[m], bfr[n], acc[m][n], 0, 0, 0);
        __syncthreads();
    }

    int colb = bn + wc*64 + (l & 15);
    #pragma unroll
    for (int m = 0; m < 4; ++m) {
        int row0 = bm + wr*64 + m*16 + (l >> 4)*4;
        #pragma unroll
        for (int r = 0; r < 4; ++r) {
            int row = row0 + r;
            int valid = 1;
            if (EPI) valid = get_valid(mask, row, u8);
            #pragma unroll
            for (int n = 0; n < 4; ++n) {
                int cc = colb + n*16;
                float val = acc[m][n][r];
                if (EPI) {
                    val = valid ? bf2f(residbf[(size_t)row*256 + cc]) + val : 0.f;
                    ((float*)C)[(size_t)row*256 + cc] = val;
                } else {
                    ((unsigned short*)C)[(size_t)row*256 + cc] = f2bf(val);
                }
            }
        }
    }
}

// ---------------- attention body (R13-proven) ----------------
__device__ __forceinline__ void attn_do(int sb, int tid, char* smem,
    const unsigned short* __restrict__ q, const unsigned short* __restrict__ k,
    const unsigned short* __restrict__ v, const int* __restrict__ idx,
    const void* __restrict__ mask, int u8, unsigned short* __restrict__ aobf) {
    int (*s_j)[16]      = (int (*)[16])smem;
    float (*s_w)[16][8] = (float (*)[16][8])(smem + 256);
    int wave = tid >> 6, lane = tid & 63;
    int t = sb * 4 + wave;
    int b = t >> 10;
    int sub = lane & 3, nbr = lane >> 2;
    int j = idx[(size_t)t*KNBR + nbr];
    if (lane < 16) s_j[wave][lane] = idx[(size_t)t*KNBR + lane];
    int nv = get_valid(mask, b*NN + j, u8);
    const unsigned short* qb = q + (size_t)t*DD;
    const unsigned short* kb = k + ((size_t)(b*NN + j))*DD;

    float w[8];
    #pragma unroll
    for (int h = 0; h < 8; ++h) {
        bf16x8 qv = *(const bf16x8*)(qb + h*32 + sub*8);
        bf16x8 kv = *(const bf16x8*)(kb + h*32 + sub*8);
        float acc = 0.f;
        #pragma unroll
        for (int e = 0; e < 8; ++e)
            acc += bf2f((unsigned short)qv[e]) * bf2f((unsigned short)kv[e]);
        acc += __shfl_xor(acc, 1);
        acc += __shfl_xor(acc, 2);
        float e = nv ? __expf(acc * 0.17677669529663688f) : 0.f;   // 1/sqrt(32)
        float sum = e;
        #pragma unroll
        for (int off = 4; off <= 32; off <<= 1) sum += __shfl_xor(sum, off);
        w[h] = e / sum;
    }
    if (sub == 0) {
        #pragma unroll
        for (int h = 0; h < 8; ++h) s_w[wave][nbr][h] = w[h];
    }
    __syncthreads();

    int c0 = lane * 4;
    int h = lane >> 3;
    float o0 = 0.f, o1 = 0.f, o2 = 0.f, o3 = 0.f;
    #pragma unroll
    for (int kk = 0; kk < 16; ++kk) {
        int jj = s_j[wave][kk];
        float wk = s_w[wave][kk][h];
        u16x4 vv = *(const u16x4*)(v + ((size_t)(b*NN + jj))*DD + c0);
        o0 += wk * bf2f(vv[0]);
        o1 += wk * bf2f(vv[1]);
        o2 += wk * bf2f(vv[2]);
        o3 += wk * bf2f(vv[3]);
    }
    u16x4 st;
    st[0] = f2bf(o0); st[1] = f2bf(o1); st[2] = f2bf(o2); st[3] = f2bf(o3);
    *(u16x4*)(aobf + (size_t)t*DD + c0) = st;
}

// ---------------- fused qkv -> attn -> out with atomic flag gates ----------------
// Blocks: [0,768) qkv | [768,4864) attn | [4864,5120) out. Consumers have HIGHER
// block ids than their producers (CP dispatches ascending), and gates are
// region-local: attn(batch b) waits cnt_qkv[b]==48; out(tile gx) waits
// cnt_attn[gx]==32. Device-scope release/acquire handles cross-XCD L2 (G16).
__global__ __launch_bounds__(256) void fused_qao(
    const unsigned short* __restrict__ xpebf, const unsigned short* __restrict__ xbf,
    const unsigned short* __restrict__ WT,
    unsigned short* __restrict__ q, unsigned short* __restrict__ k,
    unsigned short* __restrict__ v, const int* __restrict__ idx,
    const void* __restrict__ mask, const int* __restrict__ flag,
    unsigned short* __restrict__ aobf, float* __restrict__ out,
    int* __restrict__ cnt) {
    __shared__ __align__(16) char smem[16384];
    int* cnt_qkv  = cnt;        // [16]
    int* cnt_attn = cnt + 16;   // [128]
    int bid = blockIdx.x;
    int tid = threadIdx.x;

    if (bid < 768) {
        // ---- qkv GEMM (producer) ----
        int z = bid >> 8, rem = bid & 255;
        int gx = rem & 127, gy = rem >> 7;
        const unsigned short* A  = (z == 2) ? xbf : xpebf;
        const unsigned short* BT = WT + (size_t)z * 65536;
        unsigned short* C = (z == 0) ? q : (z == 1) ? k : v;
        gemm_mfma_core<0>(A, BT, C, nullptr, nullptr, 0, gx*128, gy*128, smem);
        __syncthreads();   // drain all threads' stores (vmcnt0) before fence
        if (tid == 0) {
            __threadfence();   // L2 writeback to coherent point
            __hip_atomic_fetch_add(&cnt_qkv[gx >> 3], 1,
                                   __ATOMIC_RELEASE, __HIP_MEMORY_SCOPE_AGENT);
        }
        return;
    }
    if (bid < 4864) {
        // ---- attention (consumer of qkv, producer for out) ----
        int vb = bid - 768;
        int sb = (vb & 7) * 512 + (vb >> 3);   // XCD-chunked
        int b = sb >> 8;
        if (tid == 0) {
            while (__hip_atomic_load(&cnt_qkv[b], __ATOMIC_ACQUIRE,
                                     __HIP_MEMORY_SCOPE_AGENT) < 48)
                __builtin_amdgcn_s_sleep(8);
            __threadfence();   // invalidate stale L1/L2 before data reads
        }
        __syncthreads();
        int u8 = *flag;
        attn_do(sb, tid, smem, q, k, v, idx, mask, u8, aobf);
        __syncthreads();   // drain aobf stores
        if (tid == 0) {
            __threadfence();
            __hip_atomic_fetch_add(&cnt_attn[sb >> 5], 1,
                                   __ATOMIC_RELEASE, __HIP_MEMORY_SCOPE_AGENT);
        }
        return;
    }
    {
        // ---- output GEMM (consumer of attn) ----
        int vb = bid - 4864;
        int gx = vb & 127, gy = vb >> 7;
        if (tid == 0) {
            while (__hip_atomic_load(&cnt_attn[gx], __ATOMIC_ACQUIRE,
                                     __HIP_MEMORY_SCOPE_AGENT) < 32)
                __builtin_amdgcn_s_sleep(8);
            __threadfence();
        }
        __syncthreads();
        int u8 = *flag;
        gemm_mfma_core<1>(aobf, WT + (size_t)3 * 65536, out, xbf, mask, u8,
                          gx * 128, gy * 128, smem);
    }
}

extern "C" void kernel_launch(void* const* d_in, const int* in_sizes, int n_in,
                              void* d_out, int out_size, void* d_ws, size_t ws_size,
                              hipStream_t stream) {
    const float* x    = (const float*)d_in[0];
    const float* xpos = (const float*)d_in[1];
    const void*  mask = d_in[2];
    const float* Wq   = (const float*)d_in[3];
    const float* Wk   = (const float*)d_in[4];
    const float* Wv   = (const float*)d_in[5];
    const float* Wo   = (const float*)d_in[6];
    float* out = (float*)d_out;
    char*  ws  = (char*)d_ws;
    if (ws_size < WS_NEED) return;

    int*            flag  = (int*)           (ws + OFF_FLAG);
    int*            cnt   = (int*)           (ws + OFF_CNT);
    unsigned short* xpebf = (unsigned short*)(ws + OFF_XPE);
    unsigned short* xbf   = (unsigned short*)(ws + OFF_XBF);
    unsigned short* WT    = (unsigned short*)(ws + OFF_WT);
    unsigned short* q     = (unsigned short*)(ws + OFF_Q);
    unsigned short* k     = (unsigned short*)(ws + OFF_K);
    unsigned short* v     = (unsigned short*)(ws + OFF_V);
    unsigned short* aobf  = (unsigned short*)(ws + OFF_AO);
    int*            idx   = (int*)           (ws + OFF_IDX);

    prep_fused<<<13313, 256, 0, stream>>>(xpos, idx, x, mask, flag, cnt,
                                          Wq, Wk, Wv, Wo, WT, xpebf, xbf);
    fused_qao<<<5120, 256, 0, stream>>>(xpebf, xbf, WT, q, k, v, idx,
                                        mask, flag, aobf, out, cnt);
}

// Round 16
// 79.612 us; speedup vs baseline: 6.0895x; 6.0895x over previous
//
#include <hip/hip_runtime.h>
#include <math.h>

// Problem constants
#define BB 16
#define NN 1024
#define DD 256
#define HH 8
#define DHH 32
#define KNBR 16
#define MM (BB*NN)   // 16384 tokens

typedef __attribute__((ext_vector_type(8))) short  bf16x8;
typedef __attribute__((ext_vector_type(4))) float  f32x4;
typedef __attribute__((ext_vector_type(2))) unsigned short u16x2;
typedef __attribute__((ext_vector_type(4))) unsigned short u16x4;

// ---------------- workspace layout (bytes) ----------------
#define OFF_FLAG 0
#define OFF_XPE  ((size_t)256)                          // bf16 x+pe (8 MB) — aliased by aobf later
#define OFF_XBF  (OFF_XPE + (size_t)MM*DD*2)            // bf16 x    (8 MB)
#define OFF_WT   (OFF_XBF + (size_t)MM*DD*2)            // bf16 WT[4][256][256] (512 KB)
#define OFF_Q    (OFF_WT  + (size_t)4*DD*DD*2)          // bf16 q (8 MB)
#define OFF_K    (OFF_Q   + (size_t)MM*DD*2)
#define OFF_V    (OFF_K   + (size_t)MM*DD*2)
#define OFF_AO   OFF_XPE                                // bf16 attn-out reuses xpe region
#define OFF_IDX  (OFF_V   + (size_t)MM*DD*2)
#define WS_NEED  (OFF_IDX + (size_t)MM*KNBR*4)

// ---------------- bf16 helpers ----------------
__device__ __forceinline__ float bf2f(unsigned short u) {
    unsigned x = ((unsigned)u) << 16;
    return __builtin_bit_cast(float, x);
}
__device__ __forceinline__ unsigned short f2bf(float f) {
    unsigned x = __builtin_bit_cast(unsigned, f);
    unsigned r = (x + 0x7fffu + ((x >> 16) & 1u)) >> 16;   // RNE
    return (unsigned short)r;
}
__device__ __forceinline__ int mbcnt64(unsigned long long b) {
    return __builtin_amdgcn_mbcnt_hi((unsigned)(b >> 32),
           __builtin_amdgcn_mbcnt_lo((unsigned)b, 0));
}

__device__ __forceinline__ int get_valid(const void* m, int i, int u8) {
    if (u8) return ((const unsigned char*)m)[i] != 0;
    return ((const unsigned*)m)[i] != 0u;
}

// ---------------- fused prep (R13-proven, 80.2us champion) ----------------
// block 0: mask-format detect (flag consumed by LATER kernels only — no race)
// [1,4097): KNN | [4097,5121): cvtW | [5121,13313): PE+cvt (unmasked pe is
// output-invariant: q rows zeroed by out-mask, k rows killed by score mask,
// v never sees pe) — proven R9/R10.
__global__ __launch_bounds__(256, 8) void prep_fused(
    const float* __restrict__ xpos, int* __restrict__ idxout,
    const float* __restrict__ x, const void* __restrict__ mask,
    int* __restrict__ flag,
    const float* __restrict__ Wq, const float* __restrict__ Wk,
    const float* __restrict__ Wv, const float* __restrict__ Wo,
    unsigned short* __restrict__ WT,
    unsigned short* __restrict__ xpebf, unsigned short* __restrict__ xbf) {
    __shared__ float4   sp[NN];          // 16 KB (knn)
    __shared__ unsigned scand[4][64];    // 1 KB  (knn)
    int bid = blockIdx.x;
    int tid = threadIdx.x;

    if (bid == 0) {
        // ---- mask detect: 0 = 4-byte elems (i32/f32), 1 = u8 bool ----
        __shared__ int s_u8, s_f32;
        if (tid == 0) { s_u8 = 0; s_f32 = 0; }
        __syncthreads();
        int u8 = 0, f32 = 0;
        const unsigned* mraw = (const unsigned*)mask;
        for (int i = tid; i < 4096; i += 256) {
            unsigned w = mraw[i];
            if (w == 0x3f800000u) f32 = 1;
            else if (w > 1u) u8 = 1;
        }
        if (u8)  atomicOr(&s_u8, 1);
        if (f32) atomicOr(&s_f32, 1);
        __syncthreads();
        if (tid == 0) *flag = (s_f32 ? 0 : (s_u8 ? 1 : 0));
        return;
    }
    if (bid >= 5121) {
        // ---- PE + bf16 conversion (unmasked pe) ----
        int pb = bid - 5121;
        int t = pb * 2 + (tid >> 7);
        int p = tid & 127;
        int half = p >> 6;             // 0 -> y channels [0,128), 1 -> x [128,256)
        int j = p & 63;
        float pos = xpos[(size_t)t*3 + (half ? 0 : 1)];
        float recip = 6.2831853071795864f * exp2f(-(float)j * 0.20762050593045952f);
        float th = pos * recip;
        float s, c;
        __sincosf(th, &s, &c);
        size_t o = (size_t)t*DD + half*128 + 2*j;
        float2 xv = *(const float2*)(x + o);
        u16x2 xb; xb[0] = f2bf(xv.x);     xb[1] = f2bf(xv.y);
        u16x2 xp; xp[0] = f2bf(xv.x + s); xp[1] = f2bf(xv.y + c);
        *(u16x2*)(xbf + o)   = xb;
        *(u16x2*)(xpebf + o) = xp;
        return;
    }
    if (bid >= 4097) {
        // ---- weight convert/transpose: WT[w][n][k] = bf16(W[k][n]) ----
        int g = bid - 4097;              // 0..1023
        int wsel = g >> 8;
        int kk = g & 255;
        const float* W = (wsel == 0) ? Wq : (wsel == 1) ? Wk : (wsel == 2) ? Wv : Wo;
        WT[(size_t)wsel*65536 + (size_t)tid*256 + kk] = f2bf(W[(size_t)kk*256 + tid]);
        return;
    }

    // ---- KNN: one wave per query row (proven R7 algorithm) ----
    int kb = bid - 1;
    int nblk = kb & 255;
    int b    = kb >> 8;
    for (int i = tid; i < NN; i += 256) {
        const float* p = xpos + ((size_t)b*NN + i)*3;
        float px = p[0], py = p[1], pz = p[2];
        sp[i] = make_float4(px, py, pz, px*px + py*py + pz*pz);
    }
    __syncthreads();
    int wave = tid >> 6, lane = tid & 63;
    int n = nblk * 4 + wave;
    float4 qp = sp[n];
    float d[16];
    #pragma unroll
    for (int t = 0; t < 16; ++t) {
        float4 pm = sp[lane + 64*t];
        float dot = qp.x*pm.x + qp.y*pm.y + qp.z*pm.z;
        float d2 = qp.w + pm.w - 2.f*dot;              // exact reference formula
        d[t] = fmaxf(d2, 0.f);
    }
    float lmin = d[0];
    #pragma unroll
    for (int t = 1; t < 16; ++t) lmin = fminf(lmin, d[t]);
    // bitonic sort 64 lane minima; tau = 16th smallest (>= v16)
    float xs = lmin;
    #pragma unroll
    for (int kk = 2; kk <= 64; kk <<= 1) {
        #pragma unroll
        for (int j = kk >> 1; j >= 1; j >>= 1) {
            float vv = __shfl_xor(xs, j);
            bool up = ((lane & kk) == 0);
            bool lower = ((lane & j) == 0);
            xs = (up == lower) ? fminf(xs, vv) : fmaxf(xs, vv);
        }
    }
    float tau = __shfl(xs, 15);
    int T = 0;
    #pragma unroll
    for (int t = 0; t < 16; ++t) T += (d[t] <= tau) ? 1 : 0;
    #pragma unroll
    for (int off = 1; off <= 32; off <<= 1) T += __shfl_xor(T, off);

    bool fast = (T <= 64);          // wave-uniform
    if (fast) {
        int base = 0;
        #pragma unroll
        for (int t = 0; t < 16; ++t) {
            bool c = (d[t] <= tau);
            unsigned long long bb = __ballot(c);
            if (c) scand[wave][base + mbcnt64(bb)] = __builtin_bit_cast(unsigned, d[t]);
            base += (int)__popcll(bb);
        }
    }
    __syncthreads();

    int out_base = (b*NN + n) * KNBR;
    if (fast) {
        unsigned key = (lane < T) ? scand[wave][lane] : 0xFFFFFFFFu;
        // bitonic sort 64 u32 (d2>=0: u32 order == f32 order)
        #pragma unroll
        for (int kk = 2; kk <= 64; kk <<= 1) {
            #pragma unroll
            for (int j = kk >> 1; j >= 1; j >>= 1) {
                unsigned vv = (unsigned)__shfl_xor((int)key, j);
                bool up = ((lane & kk) == 0);
                bool lower = ((lane & j) == 0);
                bool takemin = (up == lower);
                key = (takemin == (key < vv)) ? key : vv;
            }
        }
        unsigned tau2 = (unsigned)__shfl((int)key, 15);   // exact v16
        int c1 = (int)__popcll(__ballot(key < tau2));
        int lt_base = 0, eq_seen = 0;
        #pragma unroll
        for (int t = 0; t < 16; ++t) {
            unsigned du = __builtin_bit_cast(unsigned, d[t]);
            bool lt = du < tau2;
            bool eq = du == tau2;
            unsigned long long blt = __ballot(lt);
            unsigned long long beq = __ballot(eq);
            if (lt) idxout[out_base + lt_base + mbcnt64(blt)] = lane + 64*t;
            int er = eq_seen + mbcnt64(beq);
            if (eq && (c1 + er) < KNBR) idxout[out_base + c1 + er] = lane + 64*t;
            lt_base += (int)__popcll(blt);
            eq_seen += (int)__popcll(beq);
        }
    } else {
        // exact iterative fallback
        #pragma unroll 1
        for (int it = 0; it < KNBR; ++it) {
            float bd = 3.4e38f; int bm = 1 << 30;
            #pragma unroll
            for (int t = 0; t < 16; ++t)
                if (d[t] < bd) { bd = d[t]; bm = lane + 64*t; }
            #pragma unroll
            for (int off = 32; off >= 1; off >>= 1) {
                float od = __shfl_xor(bd, off);
                int   om = __shfl_xor(bm, off);
                if (od < bd || (od == bd && om < bm)) { bd = od; bm = om; }
            }
            if (lane == 0) idxout[out_base + it] = bm;
            int sel = bm >> 6;
            int mine = ((bm & 63) == lane);
            #pragma unroll
            for (int t = 0; t < 16; ++t)
                if (mine && t == sel) d[t] = 3.4e38f;
        }
    }
}

// ---------------- bf16 MFMA GEMM core (R8/R10-proven): 128x128 tile, 4 waves ----------
// EPI=1: residual read as bf16 (xbf) — rounding adds <=~0.015 abs, budget 0.119.
template<int EPI>
__device__ __forceinline__ void gemm_mfma_core(
    const unsigned short* __restrict__ A, const unsigned short* __restrict__ BT,
    void* __restrict__ C, const unsigned short* __restrict__ residbf,
    const void* __restrict__ mask, int u8, int bm, int bn, char* smem) {
    unsigned short (*As)[32] = (unsigned short (*)[32])smem;
    unsigned short (*Bs)[32] = (unsigned short (*)[32])(smem + 8192);
    int tid = threadIdx.x;
    int w = tid >> 6, l = tid & 63;
    int wr = w >> 1, wc = w & 1;

    f32x4 acc[4][4] = {};

    for (int kt = 0; kt < 8; ++kt) {
        #pragma unroll
        for (int j = 0; j < 2; ++j) {
            int c  = (w + j*4)*64 + l;        // 0..511
            int row = c >> 2;                 // 0..127
            int cb  = (c & 3) * 16;           // byte col within 64B row
            const char* ga = (const char*)A + ((size_t)(bm + row)*256 + kt*32)*2 + cb;
            char* la = (char*)As + (size_t)(w + j*4)*1024;   // wave-uniform dest
            __builtin_amdgcn_global_load_lds(
                (const __attribute__((address_space(1))) unsigned*)ga,
                (__attribute__((address_space(3))) unsigned*)la, 16, 0, 0);
            const char* gb = (const char*)BT + ((size_t)(bn + row)*256 + kt*32)*2 + cb;
            char* lb = (char*)Bs + (size_t)(w + j*4)*1024;
            __builtin_amdgcn_global_load_lds(
                (const __attribute__((address_space(1))) unsigned*)gb,
                (__attribute__((address_space(3))) unsigned*)lb, 16, 0, 0);
        }
        __syncthreads();

        bf16x8 af[4], bfr[4];
        #pragma unroll
        for (int m = 0; m < 4; ++m)
            af[m] = *(const bf16x8*)&As[wr*64 + m*16 + (l & 15)][(l >> 4) * 8];
        #pragma unroll
        for (int n = 0; n < 4; ++n)
            bfr[n] = *(const bf16x8*)&Bs[wc*64 + n*16 + (l & 15)][(l >> 4) * 8];
        #pragma unroll
        for (int m = 0; m < 4; ++m)
            #pragma unroll
            for (int n = 0; n < 4; ++n)
                acc[m][n] = __builtin_amdgcn_mfma_f32_16x16x32_bf16(af[m], bfr[n], acc[m][n], 0, 0, 0);
        __syncthreads();
    }

    // epilogue: C/D layout col = lane&15, row = (lane>>4)*4 + r  [m89-verified]
    int colb = bn + wc*64 + (l & 15);
    #pragma unroll
    for (int m = 0; m < 4; ++m) {
        int row0 = bm + wr*64 + m*16 + (l >> 4)*4;
        #pragma unroll
        for (int r = 0; r < 4; ++r) {
            int row = row0 + r;
            int valid = 1;
            if (EPI) valid = get_valid(mask, row, u8);
            #pragma unroll
            for (int n = 0; n < 4; ++n) {
                int cc = colb + n*16;
                float val = acc[m][n][r];
                if (EPI) {
                    val = valid ? bf2f(residbf[(size_t)row*256 + cc]) + val : 0.f;
                    ((float*)C)[(size_t)row*256 + cc] = val;
                } else {
                    ((unsigned short*)C)[(size_t)row*256 + cc] = f2bf(val);
                }
            }
        }
    }
}

__global__ __launch_bounds__(256) void gemm_qkv_mfma(
    const unsigned short* __restrict__ xpebf, const unsigned short* __restrict__ xbf,
    const unsigned short* __restrict__ WT,
    unsigned short* __restrict__ q, unsigned short* __restrict__ k,
    unsigned short* __restrict__ v) {
    __shared__ __align__(16) char smem[16384];
    int z = blockIdx.z;
    const unsigned short* A  = (z == 2) ? xbf : xpebf;
    const unsigned short* BT = WT + (size_t)z * 65536;
    unsigned short* C = (z == 0) ? q : (z == 1) ? k : v;
    gemm_mfma_core<0>(A, BT, C, nullptr, nullptr, 0, blockIdx.x*128, blockIdx.y*128, smem);
}

__global__ __launch_bounds__(256) void gemm_out_mfma(
    const unsigned short* __restrict__ aobf, const unsigned short* __restrict__ WT,
    const unsigned short* __restrict__ xbf, const void* __restrict__ mask,
    const int* __restrict__ flag, float* __restrict__ out) {
    __shared__ __align__(16) char smem[16384];
    int u8 = *flag;
    gemm_mfma_core<1>(aobf, WT + (size_t)3 * 65536, out, xbf, mask, u8,
                      blockIdx.x * 128, blockIdx.y * 128, smem);
}

// ---------------- local attention: one wave per token, bf16 q/k/v (R13 pattern) -------
// Max-free softmax: shift-invariant, |s|<=~20 << 88 (f32 exp range); invalid
// neighbors contribute e=0 exactly; valid queries always contain themselves
// (d2=0 -> top-16) so denom>0. Loads/dots identical to R10 (contiguous 64B
// per 4-lane group — R12 lesson: never fragment the gather).
// NO __syncthreads: s_j/s_w written and read by the SAME wave (wave-synchronous
// LDS; compiler orders via lgkmcnt — validated in R11 variant, absmax-clean).
__global__ __launch_bounds__(256) void attn_kernel(
    const unsigned short* __restrict__ q, const unsigned short* __restrict__ k,
    const unsigned short* __restrict__ v, const int* __restrict__ idx,
    const void* __restrict__ mask, const int* __restrict__ flag,
    unsigned short* __restrict__ aobf) {
    __shared__ int   s_j[4][16];
    __shared__ float s_w[4][16][8];
    int u8 = *flag;
    int wave = threadIdx.x >> 6, lane = threadIdx.x & 63;
    // XCD-chunked swizzle: 4096 blocks -> 512 consecutive blocks per XCD
    int cpx = gridDim.x >> 3;
    int sb = ((int)blockIdx.x & 7) * cpx + ((int)blockIdx.x >> 3);
    int t = sb * 4 + wave;
    int b = t >> 10;
    int sub = lane & 3, nbr = lane >> 2;
    int j = idx[(size_t)t*KNBR + nbr];
    if (lane < 16) s_j[wave][lane] = idx[(size_t)t*KNBR + lane];
    int nv = get_valid(mask, b*NN + j, u8);
    const unsigned short* qb = q + (size_t)t*DD;
    const unsigned short* kb = k + ((size_t)(b*NN + j))*DD;

    float w[8];
    #pragma unroll
    for (int h = 0; h < 8; ++h) {
        bf16x8 qv = *(const bf16x8*)(qb + h*32 + sub*8);
        bf16x8 kv = *(const bf16x8*)(kb + h*32 + sub*8);
        float acc = 0.f;
        #pragma unroll
        for (int e = 0; e < 8; ++e)
            acc += bf2f((unsigned short)qv[e]) * bf2f((unsigned short)kv[e]);
        acc += __shfl_xor(acc, 1);
        acc += __shfl_xor(acc, 2);
        float e = nv ? __expf(acc * 0.17677669529663688f) : 0.f;   // 1/sqrt(32)
        float sum = e;
        #pragma unroll
        for (int off = 4; off <= 32; off <<= 1) sum += __shfl_xor(sum, off);
        w[h] = e / sum;
    }
    if (sub == 0) {
        #pragma unroll
        for (int h = 0; h < 8; ++h) s_w[wave][nbr][h] = w[h];
    }
    // (no barrier: same-wave producer/consumer)

    // PV: channel c0 = lane*4 .. +3, head h = lane>>3
    int c0 = lane * 4;
    int h = lane >> 3;
    float o0 = 0.f, o1 = 0.f, o2 = 0.f, o3 = 0.f;
    #pragma unroll
    for (int kk = 0; kk < 16; ++kk) {
        int jj = s_j[wave][kk];
        float wk = s_w[wave][kk][h];
        u16x4 vv = *(const u16x4*)(v + ((size_t)(b*NN + jj))*DD + c0);
        o0 += wk * bf2f(vv[0]);
        o1 += wk * bf2f(vv[1]);
        o2 += wk * bf2f(vv[2]);
        o3 += wk * bf2f(vv[3]);
    }
    u16x4 st;
    st[0] = f2bf(o0); st[1] = f2bf(o1); st[2] = f2bf(o2); st[3] = f2bf(o3);
    *(u16x4*)(aobf + (size_t)t*DD + c0) = st;
}

extern "C" void kernel_launch(void* const* d_in, const int* in_sizes, int n_in,
                              void* d_out, int out_size, void* d_ws, size_t ws_size,
                              hipStream_t stream) {
    const float* x    = (const float*)d_in[0];
    const float* xpos = (const float*)d_in[1];
    const void*  mask = d_in[2];
    const float* Wq   = (const float*)d_in[3];
    const float* Wk   = (const float*)d_in[4];
    const float* Wv   = (const float*)d_in[5];
    const float* Wo   = (const float*)d_in[6];
    float* out = (float*)d_out;
    char*  ws  = (char*)d_ws;
    if (ws_size < WS_NEED) return;

    int*            flag  = (int*)           (ws + OFF_FLAG);
    unsigned short* xpebf = (unsigned short*)(ws + OFF_XPE);
    unsigned short* xbf   = (unsigned short*)(ws + OFF_XBF);
    unsigned short* WT    = (unsigned short*)(ws + OFF_WT);
    unsigned short* q     = (unsigned short*)(ws + OFF_Q);
    unsigned short* k     = (unsigned short*)(ws + OFF_K);
    unsigned short* v     = (unsigned short*)(ws + OFF_V);
    unsigned short* aobf  = (unsigned short*)(ws + OFF_AO);
    int*            idx   = (int*)           (ws + OFF_IDX);

    prep_fused<<<13313, 256, 0, stream>>>(xpos, idx, x, mask, flag,
                                          Wq, Wk, Wv, Wo, WT, xpebf, xbf);
    gemm_qkv_mfma<<<dim3(128, 2, 3), 256, 0, stream>>>(xpebf, xbf, WT, q, k, v);
    attn_kernel<<<MM/4, 256, 0, stream>>>(q, k, v, idx, mask, flag, aobf);
    gemm_out_mfma<<<dim3(128, 2), 256, 0, stream>>>(aobf, WT, xbf, mask, flag, out);
}